// Round 9
// baseline (172.539 us; speedup 1.0000x reference)
//
#include <hip/hip_runtime.h>
#include <math.h>

// loss = ALPHA * mean(level_w * (softplus(x) - x*t))
//      + BETA  * sum_{b,e} relu(sig(x[b,dst]) - sig(x[b,src])) / (B*N)
// (scatter target of the consistency add is irrelevant to the mean)
//
// R8: persistent pipelined blocks. Diagnosis: all prior rounds pinned at
// FETCH(66MB)/1.35 TB/s because phase-1 loads burst once per block then VMEM
// goes idle, and __syncthreads' vmcnt(0) drain forbids loads in flight
// across phase boundaries. Now: grid 256 x 1024 thr (1 block/CU), G=4
// groups of R=4 rows, double-buffered 2x32KB LDS, prefetch of group g+1's
// x/t issued BEFORE a custom lgkmcnt-only barrier (inline asm, no vmcnt
// drain) so 8 cache lines/thread stay in flight through phase2(g).
// Edge indices identical across groups -> cached in registers once.

#define ALPHA_C 1.0f
#define BETA_C  0.5f

constexpr int B = 4096;
constexpr int N = 4096;
constexpr int E = 16384;
constexpr int THREADS = 1024;
constexpr int R = 4;                     // rows per group
constexpr int G = 4;                     // groups per block
constexpr int GRID = B / (R * G);        // 256 blocks = 1/CU
constexpr int EJ = E / 4 / THREADS;      // 4 edge-index batches

typedef _Float16 h4 __attribute__((ext_vector_type(4)));

__global__ __launch_bounds__(64) void init_out_kernel(float* out) {
    if (threadIdx.x == 0) out[0] = 0.0f;
}

__device__ __forceinline__ void fast_sig_sp(float x, float& p, float& sp) {
    // q = exp(-|x|) in (0,1]; both sigmoid and softplus from one exp
    float q = __expf(-fabsf(x));
    float d = 1.0f + q;
    float r = __builtin_amdgcn_rcpf(d);     // ~1 ulp approx reciprocal
    p  = (x >= 0.0f) ? r : q * r;           // sigmoid
    sp = fmaxf(x, 0.0f) + __logf(d);        // softplus = max(x,0)+log(1+q)
}

__global__ __launch_bounds__(THREADS, 4) void hier_loss_kernel(
    const float* __restrict__ outputs,
    const float* __restrict__ targets,
    const float* __restrict__ level_w,
    const int*   __restrict__ edge_src,
    const int*   __restrict__ edge_dst,
    float*       __restrict__ out)
{
    __shared__ h4 Pbuf[2][N];       // 2 x 32 KB double buffer

    const int tid  = threadIdx.x;
    const int row0 = blockIdx.x * (R * G);   // 16 rows per block

    const float4* out4 = (const float4*)outputs;
    const float4* tgt4 = (const float4*)targets;
    const float4* lw4  = (const float4*)level_w;
    const int4*   es4  = (const int4*)edge_src;
    const int4*   ed4  = (const int4*)edge_dst;

    // ---- edge indices are the SAME for every group: cache once in regs ----
    int4 sc[EJ], dc[EJ];
#pragma unroll
    for (int j = 0; j < EJ; ++j) {
        sc[j] = es4[tid + j * THREADS];
        dc[j] = ed4[tid + j * THREADS];
    }
    const float4 w = lw4[tid];               // same columns every group
    const float wv[4] = {w.x, w.y, w.z, w.w};

    // ---- prologue: payload for group 0 (8 cache lines in flight) ----
    float4 xs[R], tt[R];
#pragma unroll
    for (int r = 0; r < R; ++r) {
        const size_t off = (size_t)(row0 + r) * (N / 4) + tid;
        xs[r] = out4[off];
        tt[r] = tgt4[off];
    }

    float s1 = 0.0f, s2 = 0.0f;

#pragma unroll
    for (int g = 0; g < G; ++g) {
        h4* P = Pbuf[g & 1];

        // ---- compute P(g) + BCE partial from payload regs ----
        h4 tmp[4];                  // tmp[k][r] = p(row, node 4*tid+k)
#pragma unroll
        for (int r = 0; r < R; ++r) {
            const float xv[4] = {xs[r].x, xs[r].y, xs[r].z, xs[r].w};
            const float tv[4] = {tt[r].x, tt[r].y, tt[r].z, tt[r].w};
#pragma unroll
            for (int k = 0; k < 4; ++k) {
                float p, sp;
                fast_sig_sp(xv[k], p, sp);
                s1 = fmaf(wv[k], sp - xv[k] * tv[k], s1);
                tmp[k][r] = (_Float16)p;
            }
        }
#pragma unroll
        for (int k = 0; k < 4; ++k) P[4 * tid + k] = tmp[k];  // ds_write_b128

        // ---- prefetch group g+1 payload: stays in flight through phase 2 ----
        if (g + 1 < G) {
#pragma unroll
            for (int r = 0; r < R; ++r) {
                const size_t off = (size_t)(row0 + (g + 1) * R + r) * (N / 4) + tid;
                xs[r] = out4[off];
                tt[r] = tgt4[off];
            }
        }

        // ---- barrier WITHOUT vmcnt drain: publish LDS writes only.
        // (register-destined global loads need no drain at a barrier;
        //  __syncthreads would insert s_waitcnt vmcnt(0) and kill overlap)
        asm volatile("s_waitcnt lgkmcnt(0)\n\ts_barrier" ::: "memory");

        // ---- phase 2: edge gathers on P(g); indices already in regs ----
        h4 acc0 = {0, 0, 0, 0};
        h4 acc1 = {0, 0, 0, 0};
        const h4 zero = {0, 0, 0, 0};
#pragma unroll
        for (int j = 0; j < EJ; ++j) {
            h4 a0 = P[sc[j].x], c0 = P[dc[j].x];
            h4 a1 = P[sc[j].y], c1 = P[dc[j].y];
            h4 a2 = P[sc[j].z], c2 = P[dc[j].z];
            h4 a3 = P[sc[j].w], c3 = P[dc[j].w];
            acc0 += __builtin_elementwise_max(c0 - a0, zero);   // v_pk_* fp16
            acc1 += __builtin_elementwise_max(c1 - a1, zero);
            acc0 += __builtin_elementwise_max(c2 - a2, zero);
            acc1 += __builtin_elementwise_max(c3 - a3, zero);
        }
#pragma unroll
        for (int l = 0; l < 4; ++l) s2 += (float)acc0[l] + (float)acc1[l];
        // no trailing barrier: iteration g+1's barrier separates the next
        // write of Pbuf[g&1] (at iter g+2) from this read — proven safe.
    }

    // ---- block reduce: wave64 shuffle, cross-wave via reused LDS ----
#pragma unroll
    for (int off = 32; off > 0; off >>= 1) {
        s1 += __shfl_down(s1, off, 64);
        s2 += __shfl_down(s2, off, 64);
    }
    __syncthreads();                     // full barrier before LDS reuse (tail)
    float* red = (float*)&Pbuf[0][0];
    const int wave = tid >> 6;           // 16 waves
    const int lane = tid & 63;
    if (lane == 0) { red[wave] = s1; red[16 + wave] = s2; }
    __syncthreads();
    if (tid == 0) {
        float a = 0.0f, c = 0.0f;
#pragma unroll
        for (int wv2 = 0; wv2 < 16; ++wv2) { a += red[wv2]; c += red[16 + wv2]; }
        const float inv = 1.0f / ((float)B * (float)N);
        atomicAdd(out, (ALPHA_C * a + BETA_C * c) * inv);
    }
}

extern "C" void kernel_launch(void* const* d_in, const int* in_sizes, int n_in,
                              void* d_out, int out_size, void* d_ws, size_t ws_size,
                              hipStream_t stream) {
    const float* outputs = (const float*)d_in[0];
    const float* targets = (const float*)d_in[1];
    const float* level_w = (const float*)d_in[2];
    const int*   edge_src = (const int*)d_in[3];
    const int*   edge_dst = (const int*)d_in[4];
    float* out = (float*)d_out;

    init_out_kernel<<<1, 64, 0, stream>>>(out);
    hier_loss_kernel<<<GRID, THREADS, 0, stream>>>(outputs, targets, level_w,
                                                   edge_src, edge_dst, out);
}